// Round 1
// baseline (407.607 us; speedup 1.0000x reference)
//
#include <hip/hip_runtime.h>

typedef __bf16 bf16;
typedef __bf16 bf16x4 __attribute__((ext_vector_type(4)));
typedef __bf16 bf16x8 __attribute__((ext_vector_type(8)));
typedef float  f32x2  __attribute__((ext_vector_type(2)));
typedef float  f32x4  __attribute__((ext_vector_type(4)));

#define NJ 75
#define JP 80
#define MID 128
#define NH 256
#define LN_EPS 1e-5f
#define XT_S 104   // x_t stride (bf16), 16B-mult, ~2-way banks
#define H1_S 104   // h1_t stride
#define GS_S 136   // g_s stride

#define MFMA16(a,b,c) __builtin_amdgcn_mfma_f32_16x16x32_bf16((a),(b),(c),0,0,0)

static __device__ __forceinline__ f32x4 f4z() { f32x4 v = {0.f,0.f,0.f,0.f}; return v; }

__global__ __launch_bounds__(256, 2)
void ke_fused(const float* __restrict__ gx,  const float* __restrict__ gA,
              const float* __restrict__ gW1, const float* __restrict__ gg1, const float* __restrict__ gb1,
              const float* __restrict__ gW2, const float* __restrict__ gg2, const float* __restrict__ gb2,
              const float* __restrict__ gWp, const float* __restrict__ gbp,
              float* __restrict__ gout, int B)
{
  __shared__ __align__(16) bf16 x_t[16*XT_S];    // x^T, rows=coord(3,pad16), cols=joint(pad96)
  __shared__ __align__(16) bf16 h_s[JP*8];       // h=A@x, [j][c3 pad8]
  __shared__ __align__(16) bf16 h1_t[MID*H1_S];  // h1^T: [c][j pad96]
  __shared__ __align__(16) bf16 g_s[JP*GS_S];    // g=(A@h1): [j][c]
  __shared__ __align__(16) float x_f32[228];
  __shared__ __align__(16) float red[JP*8];      // per-wave LN partials (s,q) x 4 waves
  __shared__ __align__(16) float fin[JP*2];      // (mu, rsig)
  __shared__ __align__(16) float skip_s[NH];
  __shared__ __align__(16) float g2b2[NH*2];
  __shared__ float xbar_s[4];

  const int tid = threadIdx.x;
  const int w   = tid >> 6;
  const int l   = tid & 63;
  const int l16 = l & 15;
  const int lg  = l >> 4;

  // ---------------- prologue (once per block) ----------------
  for (int i = tid; i < 16*XT_S;  i += 256) x_t[i]  = (bf16)0.f;
  for (int i = tid; i < JP*8;     i += 256) h_s[i]  = (bf16)0.f;
  for (int i = tid; i < MID*H1_S; i += 256) h1_t[i] = (bf16)0.f;
  for (int i = tid; i < JP*GS_S;  i += 256) g_s[i]  = (bf16)0.f;

  // persistent A fragments: frag[t][ks]: lane holds A[t*16+l16][ks*32+lg*8+e]
  bf16x8 Afrag[5][3];
  #pragma unroll
  for (int t = 0; t < 5; ++t) {
    const int r = t*16 + l16;
    #pragma unroll
    for (int ks = 0; ks < 3; ++ks) {
      bf16x8 v;
      #pragma unroll
      for (int e = 0; e < 8; ++e) {
        const int k = ks*32 + lg*8 + e;
        v[e] = (bf16)((r < NJ && k < NJ) ? gA[r*NJ + k] : 0.f);
      }
      Afrag[t][ks] = v;
    }
  }
  // W1 fragments (B-op of h@W1^T): wave owns channels [32w,32w+32)
  bf16x8 W1frag[2];
  #pragma unroll
  for (int i = 0; i < 2; ++i) {
    const int c = (2*w + i)*16 + l16;
    bf16x8 v;
    #pragma unroll
    for (int e = 0; e < 8; ++e) {
      const int k = lg*8 + e;
      v[e] = (bf16)((k < 3) ? gW1[c*3 + k] : 0.f);
    }
    W1frag[i] = v;
  }
  // W2 fragments (A-op of W2@g^T): wave owns o in [64w,64w+64)
  bf16x8 W2frag[4][4];
  #pragma unroll
  for (int m2 = 0; m2 < 4; ++m2) {
    const int o = w*64 + m2*16 + l16;
    #pragma unroll
    for (int ks = 0; ks < 4; ++ks) {
      const int c0 = ks*32 + lg*8;
      bf16x8 v;
      #pragma unroll
      for (int e = 0; e < 8; ++e) v[e] = (bf16)gW2[o*MID + c0 + e];
      W2frag[m2][ks] = v;
    }
  }
  float g1r[2], b1r[2];
  #pragma unroll
  for (int i = 0; i < 2; ++i) { const int c = (2*w+i)*16 + l16; g1r[i] = gg1[c]; b1r[i] = gb1[c]; }
  if (tid < NH) { g2b2[2*tid] = gg2[tid]; g2b2[2*tid+1] = gb2[tid]; }
  const float wp0 = gWp[tid*3+0], wp1 = gWp[tid*3+1], wp2 = gWp[tid*3+2], bpr = gbp[tid];
  __syncthreads();

  // ---------------- frame loop ----------------
  for (int f = blockIdx.x; f < B; f += gridDim.x) {
    // P0: load x
    if (tid < NJ*3) {
      const float v = gx[f*(NJ*3) + tid];
      x_f32[tid] = v;
      const int j = tid/3;
      x_t[(tid - 3*j)*XT_S + j] = (bf16)v;
    }
    __syncthreads(); // b1

    // wave0: xbar for the skip branch
    if (w == 0) {
      float s0 = 0.f, s1 = 0.f, s2 = 0.f;
      if (l < NJ)      { s0  = x_f32[l*3];      s1  = x_f32[l*3+1];      s2  = x_f32[l*3+2]; }
      if (l + 64 < NJ) { s0 += x_f32[(l+64)*3]; s1 += x_f32[(l+64)*3+1]; s2 += x_f32[(l+64)*3+2]; }
      #pragma unroll
      for (int m = 32; m >= 1; m >>= 1) {
        s0 += __shfl_xor(s0, m); s1 += __shfl_xor(s1, m); s2 += __shfl_xor(s2, m);
      }
      if (l == 0) { xbar_s[0] = s0*(1.f/NJ); xbar_s[1] = s1*(1.f/NJ); xbar_s[2] = s2*(1.f/NJ); }
    }

    // P1: h^T = x^T @ A  (A symmetric => h = A@x); redundant across waves (tiny)
    {
      f32x4 acc[5];
      #pragma unroll
      for (int nt = 0; nt < 5; ++nt) acc[nt] = f4z();
      #pragma unroll
      for (int ks = 0; ks < 3; ++ks) {
        const bf16x8 xf8 = *(const bf16x8*)&x_t[l16*XT_S + ks*32 + lg*8];
        #pragma unroll
        for (int nt = 0; nt < 5; ++nt)
          acc[nt] = MFMA16(xf8, Afrag[nt][ks], acc[nt]);
      }
      if (lg < 2) {
        #pragma unroll
        for (int nt = 0; nt < 5; ++nt) {
          if (w == (nt < 4 ? nt : 3)) {
            const int j = nt*16 + l16;
            bf16x4 p;
            #pragma unroll
            for (int r = 0; r < 4; ++r) p[r] = (bf16)acc[nt][r];
            *(bf16x4*)&h_s[j*8 + lg*4] = p;
          }
        }
      }
    }
    __syncthreads(); // b2

    // skip projection (needs xbar)
    {
      const float xb0 = xbar_s[0], xb1 = xbar_s[1], xb2 = xbar_s[2];
      skip_s[tid] = bpr + wp0*xb0 + wp1*xb1 + wp2*xb2;
    }

    // P2: h1pre = h @ W1^T  (wave owns channels [32w,32w+32))
    f32x4 acc1[5][2];
    #pragma unroll
    for (int mt = 0; mt < 5; ++mt) { acc1[mt][0] = f4z(); acc1[mt][1] = f4z(); }
    #pragma unroll
    for (int mt = 0; mt < 5; ++mt) {
      const bf16x8 hf = *(const bf16x8*)&h_s[(mt*16 + l16)*8]; // k>=8 lanes multiply W1frag zeros
      acc1[mt][0] = MFMA16(hf, W1frag[0], acc1[mt][0]);
      acc1[mt][1] = MFMA16(hf, W1frag[1], acc1[mt][1]);
    }
    // LN1 partials (sum over this wave's 32 channels)
    #pragma unroll
    for (int mt = 0; mt < 5; ++mt) {
      f32x4 sv, qv;
      #pragma unroll
      for (int r = 0; r < 4; ++r) {
        const float a0 = acc1[mt][0][r], a1 = acc1[mt][1][r];
        sv[r] = a0 + a1; qv[r] = a0*a0 + a1*a1;
      }
      #pragma unroll
      for (int m = 8; m >= 1; m >>= 1) {
        #pragma unroll
        for (int r = 0; r < 4; ++r) { sv[r] += __shfl_xor(sv[r], m); qv[r] += __shfl_xor(qv[r], m); }
      }
      if (l16 == 0) {
        #pragma unroll
        for (int r = 0; r < 4; ++r) {
          const int j = mt*16 + lg*4 + r;
          f32x2 sq = {sv[r], qv[r]};
          *(f32x2*)&red[j*8 + w*2] = sq;
        }
      }
    }
    __syncthreads(); // b3
    if (tid < JP) {
      const f32x4 a = *(const f32x4*)&red[tid*8];
      const f32x4 b = *(const f32x4*)&red[tid*8 + 4];
      const float S = a[0]+a[2]+b[0]+b[2];
      const float Q = a[1]+a[3]+b[1]+b[3];
      const float mu  = S * (1.f/128.f);
      const float var = Q * (1.f/128.f) - mu*mu;
      f32x2 mrs = {mu, rsqrtf(var + LN_EPS)};
      *(f32x2*)&fin[tid*2] = mrs;
    }
    __syncthreads(); // b4

    // LN1 apply + ReLU -> h1_t (same wave re-reads its own channel rows: no barrier)
    #pragma unroll
    for (int mt = 0; mt < 5; ++mt) {
      f32x2 mr[4];
      #pragma unroll
      for (int r = 0; r < 4; ++r) mr[r] = *(const f32x2*)&fin[(mt*16 + lg*4 + r)*2];
      #pragma unroll
      for (int i = 0; i < 2; ++i) {
        const int c = (2*w + i)*16 + l16;
        bf16x4 p;
        #pragma unroll
        for (int r = 0; r < 4; ++r) {
          const float v = (acc1[mt][i][r] - mr[r][0]) * mr[r][1] * g1r[i] + b1r[i];
          p[r] = (bf16)fmaxf(v, 0.f);
        }
        *(bf16x4*)&h1_t[c*H1_S + mt*16 + lg*4] = p;
      }
    }

    // P3: g^T = h1^T @ A (wave owns its 32 channel-rows of h1^T)
    f32x4 accg[2][5];
    #pragma unroll
    for (int m2 = 0; m2 < 2; ++m2)
      #pragma unroll
      for (int nt = 0; nt < 5; ++nt) accg[m2][nt] = f4z();
    #pragma unroll
    for (int m2 = 0; m2 < 2; ++m2) {
      const int c = (2*w + m2)*16 + l16;
      #pragma unroll
      for (int ks = 0; ks < 3; ++ks) {
        const bf16x8 hf = *(const bf16x8*)&h1_t[c*H1_S + ks*32 + lg*8];
        #pragma unroll
        for (int nt = 0; nt < 5; ++nt)
          accg[m2][nt] = MFMA16(hf, Afrag[nt][ks], accg[m2][nt]);
      }
    }
    #pragma unroll
    for (int m2 = 0; m2 < 2; ++m2) {
      const int cb = (2*w + m2)*16 + lg*4;
      #pragma unroll
      for (int nt = 0; nt < 5; ++nt) {
        const int j = nt*16 + l16;
        bf16x4 p;
        #pragma unroll
        for (int r = 0; r < 4; ++r) p[r] = (bf16)accg[m2][nt][r];
        *(bf16x4*)&g_s[j*GS_S + cb] = p;
      }
    }
    __syncthreads(); // b6

    // P4: z^T = W2 @ g^T (wave owns o in [64w,64w+64))
    f32x4 accz[5][4];
    #pragma unroll
    for (int nt = 0; nt < 5; ++nt)
      #pragma unroll
      for (int m2 = 0; m2 < 4; ++m2) accz[nt][m2] = f4z();
    #pragma unroll
    for (int nt = 0; nt < 5; ++nt) {
      const int j = nt*16 + l16;
      #pragma unroll
      for (int ks = 0; ks < 4; ++ks) {
        const bf16x8 gf = *(const bf16x8*)&g_s[j*GS_S + ks*32 + lg*8];
        #pragma unroll
        for (int m2 = 0; m2 < 4; ++m2)
          accz[nt][m2] = MFMA16(W2frag[m2][ks], gf, accz[nt][m2]);
      }
    }
    // LN2 partials (sum over this wave's 64 output rows, in-lane 16 + xor16/32)
    #pragma unroll
    for (int nt = 0; nt < 5; ++nt) {
      float S = 0.f, Q = 0.f;
      #pragma unroll
      for (int m2 = 0; m2 < 4; ++m2)
        #pragma unroll
        for (int r = 0; r < 4; ++r) { const float v = accz[nt][m2][r]; S += v; Q += v*v; }
      S += __shfl_xor(S, 16); Q += __shfl_xor(Q, 16);
      S += __shfl_xor(S, 32); Q += __shfl_xor(Q, 32);
      if (lg == 0) { f32x2 sq = {S, Q}; *(f32x2*)&red[(nt*16 + l16)*8 + w*2] = sq; }
    }
    __syncthreads(); // b7
    if (tid < JP) {
      const f32x4 a = *(const f32x4*)&red[tid*8];
      const f32x4 b = *(const f32x4*)&red[tid*8 + 4];
      const float S = a[0]+a[2]+b[0]+b[2];
      const float Q = a[1]+a[3]+b[1]+b[3];
      const float mu  = S * (1.f/256.f);
      const float var = Q * (1.f/256.f) - mu*mu;
      f32x2 mrs = {mu, rsqrtf(var + LN_EPS)};
      *(f32x2*)&fin[tid*2] = mrs;
    }
    __syncthreads(); // b8

    // LN2 apply + ReLU + mean over j<75 + skip, coalesced f32x4 store
    #pragma unroll
    for (int m2 = 0; m2 < 4; ++m2) {
      f32x4 os = f4z();
      float gg[4], bb[4];
      #pragma unroll
      for (int r = 0; r < 4; ++r) {
        const int o = w*64 + m2*16 + lg*4 + r;
        gg[r] = g2b2[2*o]; bb[r] = g2b2[2*o+1];
      }
      #pragma unroll
      for (int nt = 0; nt < 5; ++nt) {
        const int j = nt*16 + l16;
        const f32x2 mr = *(const f32x2*)&fin[j*2];
        const bool jv = (j < NJ);
        #pragma unroll
        for (int r = 0; r < 4; ++r) {
          float v = (accz[nt][m2][r] - mr[0]) * mr[1] * gg[r] + bb[r];
          v = fmaxf(v, 0.f);
          os[r] += jv ? v : 0.f;
        }
      }
      #pragma unroll
      for (int m = 8; m >= 1; m >>= 1) {
        #pragma unroll
        for (int r = 0; r < 4; ++r) os[r] += __shfl_xor(os[r], m);
      }
      if (l16 == 0) {
        const int o0 = w*64 + m2*16 + lg*4;
        const f32x4 sk = *(const f32x4*)&skip_s[o0];
        f32x4 res;
        #pragma unroll
        for (int r = 0; r < 4; ++r) res[r] = os[r]*(1.f/NJ) + sk[r];
        *(f32x4*)&gout[f*NH + o0] = res;
      }
    }
  }
}

extern "C" void kernel_launch(void* const* d_in, const int* in_sizes, int n_in,
                              void* d_out, int out_size, void* d_ws, size_t ws_size,
                              hipStream_t stream) {
  const float* x  = (const float*)d_in[0];
  const float* A  = (const float*)d_in[1];
  const float* W1 = (const float*)d_in[2];
  const float* g1 = (const float*)d_in[3];
  const float* b1 = (const float*)d_in[4];
  const float* W2 = (const float*)d_in[5];
  const float* g2 = (const float*)d_in[6];
  const float* b2 = (const float*)d_in[7];
  const float* Wp = (const float*)d_in[8];
  const float* bp = (const float*)d_in[9];
  float* out = (float*)d_out;
  const int B = in_sizes[0] / (NJ*3);
  ke_fused<<<dim3(512), dim3(256), 0, stream>>>(x, A, W1, g1, b1, W2, g2, b2, Wp, bp, out, B);
}